// Round 1
// baseline (170.429 us; speedup 1.0000x reference)
//
#include <hip/hip_runtime.h>

// 8-bit ripple-borrow subtractor on 0/1-valued float32 rows.
// Row layout: index 7 is LSB. Output = [diffs (N,8) ; borrow (N,1)] flat.
__global__ __launch_bounds__(256) void sub8_kernel(
    const float4* __restrict__ A4, const float4* __restrict__ B4,
    const float* __restrict__ Bin, float4* __restrict__ D4,
    float* __restrict__ Bout, int n)
{
    int stride = gridDim.x * blockDim.x;
    for (int i = blockIdx.x * blockDim.x + threadIdx.x; i < n; i += stride) {
        float4 a0 = A4[2 * i];
        float4 a1 = A4[2 * i + 1];
        float4 b0 = B4[2 * i];
        float4 b1 = B4[2 * i + 1];
        bool borrow = Bin[i] != 0.0f;

        float av[8] = {a0.x, a0.y, a0.z, a0.w, a1.x, a1.y, a1.z, a1.w};
        float bv[8] = {b0.x, b0.y, b0.z, b0.w, b1.x, b1.y, b1.z, b1.w};
        float dv[8];

        // Ripple from LSB (index 7) to MSB (index 0). All values are 0/1,
        // so boolean evaluation is bit-exact vs the float-arithmetic ref.
        #pragma unroll
        for (int j = 7; j >= 0; --j) {
            bool ai = av[j] != 0.0f;
            bool bi = bv[j] != 0.0f;
            bool diff = (ai ^ bi) ^ borrow;
            bool na = !ai;
            borrow = (na && bi) || (na && borrow) || (bi && borrow);
            dv[j] = diff ? 1.0f : 0.0f;
        }

        D4[2 * i]     = make_float4(dv[0], dv[1], dv[2], dv[3]);
        D4[2 * i + 1] = make_float4(dv[4], dv[5], dv[6], dv[7]);
        Bout[i] = borrow ? 1.0f : 0.0f;
    }
}

extern "C" void kernel_launch(void* const* d_in, const int* in_sizes, int n_in,
                              void* d_out, int out_size, void* d_ws, size_t ws_size,
                              hipStream_t stream) {
    const float* A   = (const float*)d_in[0];
    const float* B   = (const float*)d_in[1];
    const float* Bin = (const float*)d_in[2];
    int n = in_sizes[0] / 8;          // number of rows

    float* D    = (float*)d_out;          // (N,8) diffs
    float* Bout = D + (size_t)n * 8;      // (N,1) borrow-out

    const int block = 256;
    int grid = (n + block - 1) / block;
    if (grid > 2048) grid = 2048;         // grid-stride the rest

    sub8_kernel<<<grid, block, 0, stream>>>(
        (const float4*)A, (const float4*)B, Bin, (float4*)D, Bout, n);
}